// Round 1
// baseline (6461.065 us; speedup 1.0000x reference)
//
#include <hip/hip_runtime.h>

// Problem constants (from reference):
//   x:              [B, C, N_OUT]      f32
//   idx_mask:       [B, C, N_OUT]      i32 in [0, K)
//   sample_map:     [N_OUT, K, P]      i32 in [0, N_IN)
//   interp_weights: [N_OUT, K, P]      f32
//   out:            [B, C, N_IN]       f32 (scatter-add)
#define BB     8
#define CC     64
#define N_OUT  65536
#define N_IN   262144
#define KK     9
#define PP     4

// ---------------------------------------------------------------------------
// Kernel 1: zero the output (512 MiB). float4 grid-stride stores.
// ---------------------------------------------------------------------------
__global__ __launch_bounds__(256) void zero_kernel(float4* __restrict__ out, int n4) {
    int i = blockIdx.x * blockDim.x + threadIdx.x;
    int stride = gridDim.x * blockDim.x;
    const float4 z = {0.f, 0.f, 0.f, 0.f};
    for (; i < n4; i += stride) out[i] = z;
}

// ---------------------------------------------------------------------------
// Kernel 2: scatter-add.
// Grid layout: blockIdx = plane * 256 + chunk   (plane-major)
//   plane = (b*C + c) in [0, 512), chunk selects 256 consecutive o's.
// Lane = consecutive o  -> x/idx reads coalesced.
// sample_map/weights row (o,k) is 16 B aligned -> int4/float4 loads.
// Atomic targets: random within the plane's 1 MiB output slice. Plane-major
// block order keeps the concurrently-active atomic footprint ~8 MiB (hot in
// the memory-side cache).
// ---------------------------------------------------------------------------
__global__ __launch_bounds__(256) void scatter_kernel(
    const float* __restrict__ x,
    const int*   __restrict__ idx_mask,
    const int4*  __restrict__ smap,   // [N_OUT*K] rows of 4 ints
    const float4* __restrict__ wts,   // [N_OUT*K] rows of 4 floats
    float* __restrict__ out)
{
    const int plane = blockIdx.x >> 8;                       // 0..511
    const int o     = ((blockIdx.x & 255) << 8) + threadIdx.x; // 0..65535

    const long ibase = (long)plane * N_OUT + o;
    const float xv = x[ibase];
    const int   k  = idx_mask[ibase];

    const int row = o * KK + k;          // (o*9 + k), row stride 16 B
    const int4   m = smap[row];
    const float4 w = wts[row];

    float* op = out + (long)plane * N_IN;
    atomicAdd(op + m.x, w.x * xv);
    atomicAdd(op + m.y, w.y * xv);
    atomicAdd(op + m.z, w.z * xv);
    atomicAdd(op + m.w, w.w * xv);
}

extern "C" void kernel_launch(void* const* d_in, const int* in_sizes, int n_in,
                              void* d_out, int out_size, void* d_ws, size_t ws_size,
                              hipStream_t stream) {
    const float* x    = (const float*)d_in[0];
    const int*   idx  = (const int*)d_in[1];
    const int4*  smap = (const int4*)d_in[2];
    const float4* wts = (const float4*)d_in[3];
    float* out = (float*)d_out;

    // Zero output: out_size = B*C*N_IN = 134,217,728 floats -> 33,554,432 float4
    const int n4 = out_size / 4;
    zero_kernel<<<4096, 256, 0, stream>>>((float4*)out, n4);

    // Scatter: one thread per (plane, o). 512 planes * 256 chunks = 131072 blocks.
    const int nblocks = (BB * CC) * (N_OUT / 256);
    scatter_kernel<<<nblocks, 256, 0, stream>>>(x, idx, smap, wts, out);
}

// Round 2
// 2438.921 us; speedup vs baseline: 2.6491x; 2.6491x over previous
//
#include <hip/hip_runtime.h>

// Problem constants:
//   x:              [B, C, N_OUT]  f32
//   idx_mask:       [B, C, N_OUT]  i32 in [0, K)
//   sample_map:     [N_OUT, K, P]  i32 in [0, N_IN)
//   interp_weights: [N_OUT, K, P]  f32
//   out:            [B, C, N_IN]   f32
#define BB     8
#define CC     64
#define N_OUT  65536
#define N_IN   262144
#define KK     9
#define PP     4
#define NE     (N_OUT * KK * PP)   // 2,359,296 inverse entries

// ---------------- d_ws layout (int units) ----------------
// counts  [N_IN]           histogram of targets
// cursor  [N_IN]           fill cursors
// offsets [N_IN+1]         CSR row offsets
// bsum    [256]            block sums for scan
// entries [NE] of int2     {pk = o<<4|k, w as f32 bits}
#define WS_COUNTS  0
#define WS_CURSOR  (N_IN)
#define WS_OFFSETS (2 * N_IN)
#define WS_BSUM    (3 * N_IN + 256)
#define WS_ENTRIES (3 * N_IN + 512)          // byte ofs % 16 == 0
#define WS_NEED_INTS (WS_ENTRIES + 2 * NE)   // ~22 MB

// ============================================================================
// CSR build
// ============================================================================
__global__ __launch_bounds__(256) void k_zero_ints(int* __restrict__ p, int n4) {
    int i = blockIdx.x * 256 + threadIdx.x;
    int stride = gridDim.x * 256;
    const int4 z = {0, 0, 0, 0};
    for (; i < n4; i += stride) ((int4*)p)[i] = z;
}

__global__ __launch_bounds__(256) void k_hist(const int* __restrict__ smap,
                                              int* __restrict__ counts) {
    int e = blockIdx.x * 256 + threadIdx.x;
    if (e < NE) atomicAdd(&counts[smap[e]], 1);
}

// scanA: 256 blocks x 1024 elems; per-block exclusive scan + block total
__global__ __launch_bounds__(256) void k_scanA(const int* __restrict__ counts,
                                               int* __restrict__ scanned,
                                               int* __restrict__ bsum) {
    __shared__ int lds[256];
    const int base = blockIdx.x * 1024 + threadIdx.x * 4;
    int4 c = *(const int4*)(counts + base);
    int s = c.x + c.y + c.z + c.w;
    lds[threadIdx.x] = s;
    __syncthreads();
    for (int off = 1; off < 256; off <<= 1) {
        int v = (threadIdx.x >= off) ? lds[threadIdx.x - off] : 0;
        __syncthreads();
        lds[threadIdx.x] += v;
        __syncthreads();
    }
    int excl = lds[threadIdx.x] - s;
    int4 o;
    o.x = excl;
    o.y = excl + c.x;
    o.z = excl + c.x + c.y;
    o.w = excl + c.x + c.y + c.z;
    *(int4*)(scanned + base) = o;
    if (threadIdx.x == 255) bsum[blockIdx.x] = lds[255];
}

// scanB: single block; exclusive scan of 256 block sums in place
__global__ __launch_bounds__(256) void k_scanB(int* __restrict__ bsum) {
    __shared__ int lds[256];
    int v = bsum[threadIdx.x];
    lds[threadIdx.x] = v;
    __syncthreads();
    for (int off = 1; off < 256; off <<= 1) {
        int t = (threadIdx.x >= off) ? lds[threadIdx.x - off] : 0;
        __syncthreads();
        lds[threadIdx.x] += t;
        __syncthreads();
    }
    bsum[threadIdx.x] = lds[threadIdx.x] - v;
}

__global__ __launch_bounds__(256) void k_scanC(int* __restrict__ scanned,
                                               const int* __restrict__ bsum) {
    const int base = blockIdx.x * 1024 + threadIdx.x * 4;
    const int add = bsum[blockIdx.x];
    int4 v = *(int4*)(scanned + base);
    v.x += add; v.y += add; v.z += add; v.w += add;
    *(int4*)(scanned + base) = v;
    if (blockIdx.x == 0 && threadIdx.x == 0) scanned[N_IN] = NE;
}

__global__ __launch_bounds__(256) void k_fill(const int* __restrict__ smap,
                                              const float* __restrict__ wts,
                                              const int* __restrict__ offsets,
                                              int* __restrict__ cursor,
                                              int2* __restrict__ entries) {
    int e = blockIdx.x * 256 + threadIdx.x;
    if (e >= NE) return;
    int n = smap[e];
    int o = e / 36;            // e = o*36 + k*4 + p
    int r = e - o * 36;
    int k = r >> 2;
    int pos = offsets[n] + atomicAdd(&cursor[n], 1);
    entries[pos] = make_int2((o << 4) | k, __float_as_int(wts[e]));
}

// ============================================================================
// Gather: 4 planes per block, idx nibbles staged in 128 KB LDS.
// Grid: 2048 blocks = 128 plane-groups x 16 n-chunks of 16384.
// XCD swizzle keeps each group's 16 chunk-blocks on one XCD -> x/idx L2-hit.
// ============================================================================
#define GTHREADS 1024
#define CHUNK_N  16384

__global__ __launch_bounds__(1024) void k_gather(
    const float* __restrict__ x,
    const int*   __restrict__ idx_mask,
    const int*   __restrict__ offsets,
    const int2*  __restrict__ entries,
    float* __restrict__ out)
{
    __shared__ unsigned short lds_k[N_OUT];   // 128 KiB: 4 nibble-planes per o

    // bijective swizzle: 2048 blocks, 256 per XCD, group-contiguous per XCD
    const int bid = blockIdx.x;
    const int l = (bid & 7) * 256 + (bid >> 3);
    const int group = l >> 4;          // 0..127
    const int chunk = l & 15;          // 0..15
    const int g4 = group * 4;

    // ---- stage idx_mask nibbles for the 4 planes ----
    const int4* i0 = (const int4*)(idx_mask + (long)(g4 + 0) * N_OUT);
    const int4* i1 = (const int4*)(idx_mask + (long)(g4 + 1) * N_OUT);
    const int4* i2 = (const int4*)(idx_mask + (long)(g4 + 2) * N_OUT);
    const int4* i3 = (const int4*)(idx_mask + (long)(g4 + 3) * N_OUT);
    uint2* lk = (uint2*)lds_k;
    #pragma unroll
    for (int it = 0; it < N_OUT / 4 / GTHREADS; ++it) {   // 16 iters
        const int q = it * GTHREADS + threadIdx.x;        // o-quad index
        int4 a = i0[q], b = i1[q], c = i2[q], d = i3[q];
        unsigned p0 = (unsigned)a.x | ((unsigned)b.x << 4) | ((unsigned)c.x << 8) | ((unsigned)d.x << 12);
        unsigned p1 = (unsigned)a.y | ((unsigned)b.y << 4) | ((unsigned)c.y << 8) | ((unsigned)d.y << 12);
        unsigned p2 = (unsigned)a.z | ((unsigned)b.z << 4) | ((unsigned)c.z << 8) | ((unsigned)d.z << 12);
        unsigned p3 = (unsigned)a.w | ((unsigned)b.w << 4) | ((unsigned)c.w << 8) | ((unsigned)d.w << 12);
        lk[q] = make_uint2(p0 | (p1 << 16), p2 | (p3 << 16));
    }
    __syncthreads();

    const float* x0 = x + (long)(g4 + 0) * N_OUT;
    const float* x1 = x + (long)(g4 + 1) * N_OUT;
    const float* x2 = x + (long)(g4 + 2) * N_OUT;
    const float* x3 = x + (long)(g4 + 3) * N_OUT;
    float* o0 = out + (long)(g4 + 0) * N_IN;
    float* o1 = out + (long)(g4 + 1) * N_IN;
    float* o2 = out + (long)(g4 + 2) * N_IN;
    float* o3 = out + (long)(g4 + 3) * N_IN;

    const int nbase = chunk * CHUNK_N;
    for (int it = 0; it < CHUNK_N / GTHREADS; ++it) {     // 16 iters
        const int n = nbase + it * GTHREADS + threadIdx.x;
        const int j0 = offsets[n];
        const int j1 = offsets[n + 1];
        float a0 = 0.f, a1 = 0.f, a2 = 0.f, a3 = 0.f;
        for (int j = j0; j < j1; ++j) {
            const int2 e = entries[j];
            const int o = e.x >> 4;
            const int k = e.x & 15;
            const float w = __int_as_float(e.y);
            const unsigned kv = lds_k[o];
            if ((int)( kv        & 15u) == k) a0 += w * x0[o];
            if ((int)((kv >>  4) & 15u) == k) a1 += w * x1[o];
            if ((int)((kv >>  8) & 15u) == k) a2 += w * x2[o];
            if ((int)( kv >> 12       ) == k) a3 += w * x3[o];
        }
        o0[n] = a0; o1[n] = a1; o2[n] = a2; o3[n] = a3;
    }
}

// ============================================================================
// Fallback (ws too small): round-1 atomic scatter
// ============================================================================
__global__ __launch_bounds__(256) void zero_kernel(float4* __restrict__ out, int n4) {
    int i = blockIdx.x * blockDim.x + threadIdx.x;
    int stride = gridDim.x * blockDim.x;
    const float4 z = {0.f, 0.f, 0.f, 0.f};
    for (; i < n4; i += stride) out[i] = z;
}

__global__ __launch_bounds__(256) void scatter_kernel(
    const float* __restrict__ x, const int* __restrict__ idx_mask,
    const int4* __restrict__ smap, const float4* __restrict__ wts,
    float* __restrict__ out)
{
    const int plane = blockIdx.x >> 8;
    const int o = ((blockIdx.x & 255) << 8) + threadIdx.x;
    const long ibase = (long)plane * N_OUT + o;
    const float xv = x[ibase];
    const int k = idx_mask[ibase];
    const int row = o * KK + k;
    const int4 m = smap[row];
    const float4 w = wts[row];
    float* op = out + (long)plane * N_IN;
    atomicAdd(op + m.x, w.x * xv);
    atomicAdd(op + m.y, w.y * xv);
    atomicAdd(op + m.z, w.z * xv);
    atomicAdd(op + m.w, w.w * xv);
}

// ============================================================================
extern "C" void kernel_launch(void* const* d_in, const int* in_sizes, int n_in,
                              void* d_out, int out_size, void* d_ws, size_t ws_size,
                              hipStream_t stream) {
    const float* x    = (const float*)d_in[0];
    const int*   idx  = (const int*)d_in[1];
    const int*   smap = (const int*)d_in[2];
    const float* wts  = (const float*)d_in[3];
    float* out = (float*)d_out;

    if (ws_size < (size_t)WS_NEED_INTS * 4) {
        // fallback: atomic scatter
        zero_kernel<<<4096, 256, 0, stream>>>((float4*)out, out_size / 4);
        scatter_kernel<<<(BB * CC) * (N_OUT / 256), 256, 0, stream>>>(
            x, idx, (const int4*)smap, (const float4*)wts, out);
        return;
    }

    int* ws = (int*)d_ws;
    int* counts  = ws + WS_COUNTS;
    int* cursor  = ws + WS_CURSOR;
    int* offsets = ws + WS_OFFSETS;
    int* bsum    = ws + WS_BSUM;
    int2* entries = (int2*)(ws + WS_ENTRIES);

    // 1) zero counts + cursor (2*N_IN ints = 131072 int4)
    k_zero_ints<<<512, 256, 0, stream>>>(counts, (2 * N_IN) / 4);
    // 2) histogram of scatter targets
    k_hist<<<NE / 256, 256, 0, stream>>>(smap, counts);
    // 3) exclusive scan -> offsets
    k_scanA<<<256, 256, 0, stream>>>(counts, offsets, bsum);
    k_scanB<<<1, 256, 0, stream>>>(bsum);
    k_scanC<<<256, 256, 0, stream>>>(offsets, bsum);
    // 4) fill CSR entries
    k_fill<<<NE / 256, 256, 0, stream>>>(smap, wts, offsets, cursor, entries);
    // 5) gather: 128 groups x 16 chunks
    k_gather<<<2048, GTHREADS, 0, stream>>>(x, idx, offsets, entries, out);
}

// Round 3
// 1331.108 us; speedup vs baseline: 4.8539x; 1.8322x over previous
//
#include <hip/hip_runtime.h>

// x:              [B, C, N_OUT]  f32
// idx_mask:       [B, C, N_OUT]  i32 in [0, K)
// sample_map:     [N_OUT, K, P]  i32 in [0, N_IN)
// interp_weights: [N_OUT, K, P]  f32
// out:            [B, C, N_IN]   f32
#define BB      8
#define CC      64
#define N_OUT   65536        // == 1<<16
#define N_IN    262144       // == 1<<18
#define KK      9
#define PP      4
#define NE      (N_OUT * KK * PP)   // 2,359,296
#define NPLANES (BB * CC)           // 512
#define GSIZE   32                  // planes per group
#define NGROUPS (NPLANES / GSIZE)   // 16
#define CHUNK   512                 // n per gather chunk
#define NCHUNKS (N_IN / CHUNK)      // 512
#define GTH     512                 // gather block threads

// ---------------- d_ws layout (int units) ----------------
#define WS_COUNTS  0
#define WS_CURSOR  (N_IN)
#define WS_OFFSETS (2 * N_IN)
#define WS_BSUM    (3 * N_IN + 256)
#define WS_ENTRIES (3 * N_IN + 512)                    // int2[NE]
#define WS_BITS    (WS_ENTRIES + 2 * NE)               // u32[NGROUPS*KK*N_OUT]
#define WS_XT      (WS_BITS + NGROUPS * KK * N_OUT)    // f32[NPLANES*N_OUT]
#define WS_END_FULL (WS_XT + NPLANES * N_OUT)
#define WS_END_NOXT WS_XT

// ============================================================================
// Build: histogram + scan + fill (CSR over n, entries carry {o,k,n_local,w})
// ============================================================================
__global__ __launch_bounds__(256) void k_zero_ints(int* __restrict__ p, int n4) {
    int i = blockIdx.x * 256 + threadIdx.x;
    int stride = gridDim.x * 256;
    const int4 z = {0, 0, 0, 0};
    for (; i < n4; i += stride) ((int4*)p)[i] = z;
}

__global__ __launch_bounds__(256) void k_hist(const int* __restrict__ smap,
                                              int* __restrict__ counts) {
    int e = blockIdx.x * 256 + threadIdx.x;
    if (e < NE) atomicAdd(&counts[smap[e]], 1);
}

__global__ __launch_bounds__(256) void k_scanA(const int* __restrict__ counts,
                                               int* __restrict__ scanned,
                                               int* __restrict__ bsum) {
    __shared__ int lds[256];
    const int base = blockIdx.x * 1024 + threadIdx.x * 4;
    int4 c = *(const int4*)(counts + base);
    int s = c.x + c.y + c.z + c.w;
    lds[threadIdx.x] = s;
    __syncthreads();
    for (int off = 1; off < 256; off <<= 1) {
        int v = (threadIdx.x >= off) ? lds[threadIdx.x - off] : 0;
        __syncthreads();
        lds[threadIdx.x] += v;
        __syncthreads();
    }
    int excl = lds[threadIdx.x] - s;
    int4 o;
    o.x = excl;
    o.y = excl + c.x;
    o.z = excl + c.x + c.y;
    o.w = excl + c.x + c.y + c.z;
    *(int4*)(scanned + base) = o;
    if (threadIdx.x == 255) bsum[blockIdx.x] = lds[255];
}

__global__ __launch_bounds__(256) void k_scanB(int* __restrict__ bsum) {
    __shared__ int lds[256];
    int v = bsum[threadIdx.x];
    lds[threadIdx.x] = v;
    __syncthreads();
    for (int off = 1; off < 256; off <<= 1) {
        int t = (threadIdx.x >= off) ? lds[threadIdx.x - off] : 0;
        __syncthreads();
        lds[threadIdx.x] += t;
        __syncthreads();
    }
    bsum[threadIdx.x] = lds[threadIdx.x] - v;
}

__global__ __launch_bounds__(256) void k_scanC(int* __restrict__ scanned,
                                               const int* __restrict__ bsum) {
    const int base = blockIdx.x * 1024 + threadIdx.x * 4;
    const int add = bsum[blockIdx.x];
    int4 v = *(int4*)(scanned + base);
    v.x += add; v.y += add; v.z += add; v.w += add;
    *(int4*)(scanned + base) = v;
    if (blockIdx.x == 0 && threadIdx.x == 0) scanned[N_IN] = NE;
}

// entry.x = (o<<16) | (k<<12) | (n & 511), entry.y = bits(w)
__global__ __launch_bounds__(256) void k_fill_v3(const int* __restrict__ smap,
                                                 const float* __restrict__ wts,
                                                 const int* __restrict__ offsets,
                                                 int* __restrict__ cursor,
                                                 int2* __restrict__ entries) {
    int e = blockIdx.x * 256 + threadIdx.x;
    if (e >= NE) return;
    int n = smap[e];
    int o = e / 36;                 // e = o*36 + k*4 + p
    int r = e - o * 36;
    int k = r >> 2;
    int pos = offsets[n] + atomicAdd(&cursor[n], 1);
    unsigned u = ((unsigned)o << 16) | ((unsigned)k << 12) | (unsigned)(n & (CHUNK - 1));
    entries[pos] = make_int2((int)u, __float_as_int(wts[e]));
}

// ============================================================================
// bits[g][k][o] : bit p set iff idx_mask[g*32+p][o] == k
// ============================================================================
#define BITS_OTILE 512
__global__ __launch_bounds__(256) void k_bits(const int* __restrict__ idx,
                                              unsigned* __restrict__ bits) {
    __shared__ unsigned lb[KK * BITS_OTILE];     // 18 KiB
    const int nob = N_OUT / BITS_OTILE;          // 128
    const int g = blockIdx.x / nob;
    const int obase = (blockIdx.x % nob) * BITS_OTILE;
    for (int i = threadIdx.x; i < KK * BITS_OTILE; i += 256) lb[i] = 0u;
    __syncthreads();
    for (int i = threadIdx.x; i < GSIZE * BITS_OTILE; i += 256) {
        int p = i >> 9;                          // BITS_OTILE == 512
        int oo = i & (BITS_OTILE - 1);
        int k = idx[((g * GSIZE + p) << 16) + obase + oo];
        atomicOr(&lb[k * BITS_OTILE + oo], 1u << p);
    }
    __syncthreads();
    for (int i = threadIdx.x; i < KK * BITS_OTILE; i += 256) {
        int k = i >> 9;
        int oo = i & (BITS_OTILE - 1);
        bits[((g * KK + k) << 16) + obase + oo] = lb[i];
    }
}

// ============================================================================
// xTg[g][o][p] = x[g*32+p][o]   (plane-transposed within each 32-group)
// ============================================================================
#define XT_OTILE 256
__global__ __launch_bounds__(256) void k_xt(const float* __restrict__ x,
                                            float* __restrict__ xt) {
    __shared__ float tile[GSIZE][XT_OTILE + 1];  // 32 x 257 f32, conflict-free
    const int nob = N_OUT / XT_OTILE;            // 256
    const int g = blockIdx.x / nob;
    const int obase = (blockIdx.x % nob) * XT_OTILE;
    for (int i = threadIdx.x; i < GSIZE * XT_OTILE; i += 256) {
        int p = i >> 8;                          // XT_OTILE == 256
        int oo = i & (XT_OTILE - 1);
        tile[p][oo] = x[((g * GSIZE + p) << 16) + obase + oo];
    }
    __syncthreads();
    for (int i = threadIdx.x; i < GSIZE * XT_OTILE; i += 256) {
        int oo = i >> 5;
        int p = i & 31;
        xt[(((size_t)(g << 16) + obase + oo) << 5) + p] = tile[p][oo];
    }
}

// ============================================================================
// Gather v3: entry-parallel, 32 planes/block, LDS f32 accumulators.
// Grid 8192 = 16 groups x 512 chunks; XCD swizzle: xcd = bid&7 owns 2 groups.
// ============================================================================
__global__ __launch_bounds__(GTH) void k_gather3(
    const float* __restrict__ x,
    const float* __restrict__ xt, int uxt,
    const int*   __restrict__ offsets,
    const int2*  __restrict__ entries,
    const unsigned* __restrict__ bits,
    float* __restrict__ out)
{
    __shared__ float acc[GSIZE * CHUNK];         // 64 KiB
    const int bid = blockIdx.x;
    const int xcd = bid & 7;
    const int r   = bid >> 3;                    // 0..1023
    const int g     = xcd * 2 + (r >> 9);
    const int chunk = r & (NCHUNKS - 1);
    const int n0    = chunk << 9;                // CHUNK == 512

    float4* a4 = (float4*)acc;
    for (int i = threadIdx.x; i < GSIZE * CHUNK / 4; i += GTH)
        a4[i] = float4{0.f, 0.f, 0.f, 0.f};
    __syncthreads();

    const int j0 = offsets[n0];
    const int j1 = offsets[n0 + CHUNK];
    const unsigned* bg = bits + ((size_t)(g * KK) << 16);

    if (uxt) {
        for (int j = j0 + threadIdx.x; j < j1; j += GTH) {
            const int2 e = entries[j];
            const unsigned u = (unsigned)e.x;
            const int o  = u >> 16;
            const int k  = (u >> 12) & 15;
            const int nl = u & (CHUNK - 1);
            const float w = __int_as_float(e.y);
            unsigned m = bg[(k << 16) + o];
            const float* xr = xt + (((size_t)(g << 16) + o) << 5);
            while (m) {
                int p = __ffs(m) - 1; m &= m - 1;
                atomicAdd(&acc[(p << 9) + nl], w * xr[p]);
            }
        }
    } else {
        for (int j = j0 + threadIdx.x; j < j1; j += GTH) {
            const int2 e = entries[j];
            const unsigned u = (unsigned)e.x;
            const int o  = u >> 16;
            const int k  = (u >> 12) & 15;
            const int nl = u & (CHUNK - 1);
            const float w = __int_as_float(e.y);
            unsigned m = bg[(k << 16) + o];
            const float* xr = x + ((size_t)(g * GSIZE) << 16) + o;
            while (m) {
                int p = __ffs(m) - 1; m &= m - 1;
                atomicAdd(&acc[(p << 9) + nl], w * xr[(size_t)p << 16]);
            }
        }
    }
    __syncthreads();

    const float4* af = (const float4*)acc;
    for (int i = threadIdx.x; i < GSIZE * CHUNK / 4; i += GTH) {
        int p  = i >> 7;                         // CHUNK/4 == 128 float4 per plane
        int n4 = i & 127;
        ((float4*)(out + (((size_t)(g * GSIZE + p)) << 18) + n0))[n4] = af[i];
    }
}

// ============================================================================
// Fallback (ws too small): round-1 atomic scatter
// ============================================================================
__global__ __launch_bounds__(256) void zero_kernel(float4* __restrict__ out, int n4) {
    int i = blockIdx.x * blockDim.x + threadIdx.x;
    int stride = gridDim.x * blockDim.x;
    const float4 z = {0.f, 0.f, 0.f, 0.f};
    for (; i < n4; i += stride) out[i] = z;
}

__global__ __launch_bounds__(256) void scatter_kernel(
    const float* __restrict__ x, const int* __restrict__ idx_mask,
    const int4* __restrict__ smap, const float4* __restrict__ wts,
    float* __restrict__ out)
{
    const int plane = blockIdx.x >> 8;
    const int o = ((blockIdx.x & 255) << 8) + threadIdx.x;
    const long ibase = (long)plane * N_OUT + o;
    const float xv = x[ibase];
    const int k = idx_mask[ibase];
    const int row = o * KK + k;
    const int4 m = smap[row];
    const float4 w = wts[row];
    float* op = out + (long)plane * N_IN;
    atomicAdd(op + m.x, w.x * xv);
    atomicAdd(op + m.y, w.y * xv);
    atomicAdd(op + m.z, w.z * xv);
    atomicAdd(op + m.w, w.w * xv);
}

// ============================================================================
extern "C" void kernel_launch(void* const* d_in, const int* in_sizes, int n_in,
                              void* d_out, int out_size, void* d_ws, size_t ws_size,
                              hipStream_t stream) {
    const float* x    = (const float*)d_in[0];
    const int*   idx  = (const int*)d_in[1];
    const int*   smap = (const int*)d_in[2];
    const float* wts  = (const float*)d_in[3];
    float* out = (float*)d_out;

    const size_t need_full = (size_t)WS_END_FULL * 4;   // ~185 MiB
    const size_t need_noxt = (size_t)WS_END_NOXT * 4;   // ~57 MiB

    if (ws_size < need_noxt) {
        zero_kernel<<<4096, 256, 0, stream>>>((float4*)out, out_size / 4);
        scatter_kernel<<<(NPLANES) * (N_OUT / 256), 256, 0, stream>>>(
            x, idx, (const int4*)smap, (const float4*)wts, out);
        return;
    }

    int* ws = (int*)d_ws;
    int* counts   = ws + WS_COUNTS;
    int* cursor   = ws + WS_CURSOR;
    int* offsets  = ws + WS_OFFSETS;
    int* bsum     = ws + WS_BSUM;
    int2* entries = (int2*)(ws + WS_ENTRIES);
    unsigned* bits = (unsigned*)(ws + WS_BITS);
    float* xt      = (float*)(ws + WS_XT);
    const int uxt = (ws_size >= need_full) ? 1 : 0;

    // 1) zero counts + cursor
    k_zero_ints<<<512, 256, 0, stream>>>(counts, (2 * N_IN) / 4);
    // 2) histogram of scatter targets
    k_hist<<<NE / 256, 256, 0, stream>>>(smap, counts);
    // 3) exclusive scan -> offsets
    k_scanA<<<256, 256, 0, stream>>>(counts, offsets, bsum);
    k_scanB<<<1, 256, 0, stream>>>(bsum);
    k_scanC<<<256, 256, 0, stream>>>(offsets, bsum);
    // 4) fill CSR entries (with n_local embedded)
    k_fill_v3<<<NE / 256, 256, 0, stream>>>(smap, wts, offsets, cursor, entries);
    // 5) per-group k-match bitmasks
    k_bits<<<NGROUPS * (N_OUT / BITS_OTILE), 256, 0, stream>>>(idx, bits);
    // 6) plane-transposed x (optional)
    if (uxt) k_xt<<<NGROUPS * (N_OUT / XT_OTILE), 256, 0, stream>>>(x, xt);
    // 7) entry-parallel gather with LDS accumulation
    k_gather3<<<NGROUPS * NCHUNKS, GTH, 0, stream>>>(x, xt, uxt, offsets, entries, bits, out);
}

// Round 5
// 1173.681 us; speedup vs baseline: 5.5050x; 1.1341x over previous
//
#include <hip/hip_runtime.h>

// x:              [B, C, N_OUT]  f32
// idx_mask:       [B, C, N_OUT]  i32 in [0, K)
// sample_map:     [N_OUT, K, P]  i32 in [0, N_IN)
// interp_weights: [N_OUT, K, P]  f32
// out:            [B, C, N_IN]   f32
#define BB      8
#define CC      64
#define N_OUT   65536        // == 1<<16
#define N_IN    262144       // == 1<<18
#define KK      9
#define PP      4
#define NE      (N_OUT * KK * PP)   // 2,359,296
#define NPLANES (BB * CC)           // 512
#define GSIZE   32                  // planes per group
#define NGROUPS (NPLANES / GSIZE)   // 16
#define CHUNK   512                 // n per gather chunk
#define NCHUNKS (N_IN / CHUNK)      // 512
#define GTH     512                 // gather block threads

typedef float f4_t __attribute__((ext_vector_type(4)));  // native vec for nontemporal

// Counting-sort key: (chunk << 9) | (o >> 7)  -> key space == N_IN exactly,
// so counts/cursor/offsets arrays and the 3-kernel scan are reused as-is.

// ---------------- d_ws layout (int units) ----------------
#define WS_COUNTS  0
#define WS_CURSOR  (N_IN)
#define WS_OFFSETS (2 * N_IN)
#define WS_BSUM    (3 * N_IN + 256)
#define WS_ENTRIES (3 * N_IN + 512)                    // int2[NE]
#define WS_BITS    (WS_ENTRIES + 2 * NE)               // u32[NGROUPS*KK*N_OUT]
#define WS_XT      (WS_BITS + NGROUPS * KK * N_OUT)    // f32[NPLANES*N_OUT]
#define WS_END_FULL (WS_XT + NPLANES * N_OUT)
#define WS_END_NOXT WS_XT

// ============================================================================
__global__ __launch_bounds__(256) void k_zero_ints(int* __restrict__ p, int n4) {
    int i = blockIdx.x * 256 + threadIdx.x;
    int stride = gridDim.x * 256;
    const int4 z = {0, 0, 0, 0};
    for (; i < n4; i += stride) ((int4*)p)[i] = z;
}

// histogram over sort keys (chunk, o_hi)
__global__ __launch_bounds__(256) void k_hist(const int* __restrict__ smap,
                                              int* __restrict__ counts) {
    int e = blockIdx.x * 256 + threadIdx.x;
    if (e >= NE) return;
    int n = smap[e];
    int o = e / 36;
    int key = ((n >> 9) << 9) | (o >> 7);
    atomicAdd(&counts[key], 1);
}

__global__ __launch_bounds__(256) void k_scanA(const int* __restrict__ counts,
                                               int* __restrict__ scanned,
                                               int* __restrict__ bsum) {
    __shared__ int lds[256];
    const int base = blockIdx.x * 1024 + threadIdx.x * 4;
    int4 c = *(const int4*)(counts + base);
    int s = c.x + c.y + c.z + c.w;
    lds[threadIdx.x] = s;
    __syncthreads();
    for (int off = 1; off < 256; off <<= 1) {
        int v = (threadIdx.x >= off) ? lds[threadIdx.x - off] : 0;
        __syncthreads();
        lds[threadIdx.x] += v;
        __syncthreads();
    }
    int excl = lds[threadIdx.x] - s;
    int4 o;
    o.x = excl;
    o.y = excl + c.x;
    o.z = excl + c.x + c.y;
    o.w = excl + c.x + c.y + c.z;
    *(int4*)(scanned + base) = o;
    if (threadIdx.x == 255) bsum[blockIdx.x] = lds[255];
}

__global__ __launch_bounds__(256) void k_scanB(int* __restrict__ bsum) {
    __shared__ int lds[256];
    int v = bsum[threadIdx.x];
    lds[threadIdx.x] = v;
    __syncthreads();
    for (int off = 1; off < 256; off <<= 1) {
        int t = (threadIdx.x >= off) ? lds[threadIdx.x - off] : 0;
        __syncthreads();
        lds[threadIdx.x] += t;
        __syncthreads();
    }
    bsum[threadIdx.x] = lds[threadIdx.x] - v;
}

__global__ __launch_bounds__(256) void k_scanC(int* __restrict__ scanned,
                                               const int* __restrict__ bsum) {
    const int base = blockIdx.x * 1024 + threadIdx.x * 4;
    const int add = bsum[blockIdx.x];
    int4 v = *(int4*)(scanned + base);
    v.x += add; v.y += add; v.z += add; v.w += add;
    *(int4*)(scanned + base) = v;
    if (blockIdx.x == 0 && threadIdx.x == 0) scanned[N_IN] = NE;
}

// entry.x = (o<<16) | (k<<12) | (n & 511), entry.y = bits(w)
// placed into its (chunk, o>>7) bucket -> chunk ranges are o-sorted (128-o grain)
__global__ __launch_bounds__(256) void k_fill(const int* __restrict__ smap,
                                              const float* __restrict__ wts,
                                              const int* __restrict__ offsets,
                                              int* __restrict__ cursor,
                                              int2* __restrict__ entries) {
    int e = blockIdx.x * 256 + threadIdx.x;
    if (e >= NE) return;
    int n = smap[e];
    int o = e / 36;                 // e = o*36 + k*4 + p
    int r = e - o * 36;
    int k = r >> 2;
    int key = ((n >> 9) << 9) | (o >> 7);
    int pos = offsets[key] + atomicAdd(&cursor[key], 1);
    unsigned u = ((unsigned)o << 16) | ((unsigned)k << 12) | (unsigned)(n & (CHUNK - 1));
    entries[pos] = make_int2((int)u, __float_as_int(wts[e]));
}

// ============================================================================
// bits[g][k][o] : bit p set iff idx_mask[g*32+p][o] == k
// ============================================================================
#define BITS_OTILE 512
__global__ __launch_bounds__(256) void k_bits(const int* __restrict__ idx,
                                              unsigned* __restrict__ bits) {
    __shared__ unsigned lb[KK * BITS_OTILE];     // 18 KiB
    const int nob = N_OUT / BITS_OTILE;          // 128
    const int g = blockIdx.x / nob;
    const int obase = (blockIdx.x % nob) * BITS_OTILE;
    for (int i = threadIdx.x; i < KK * BITS_OTILE; i += 256) lb[i] = 0u;
    __syncthreads();
    for (int i = threadIdx.x; i < GSIZE * BITS_OTILE; i += 256) {
        int p = i >> 9;
        int oo = i & (BITS_OTILE - 1);
        int k = idx[((g * GSIZE + p) << 16) + obase + oo];
        atomicOr(&lb[k * BITS_OTILE + oo], 1u << p);
    }
    __syncthreads();
    for (int i = threadIdx.x; i < KK * BITS_OTILE; i += 256) {
        int k = i >> 9;
        int oo = i & (BITS_OTILE - 1);
        bits[((g * KK + k) << 16) + obase + oo] = lb[i];
    }
}

// ============================================================================
// xTg[g][o][p] = x[g*32+p][o]
// ============================================================================
#define XT_OTILE 256
__global__ __launch_bounds__(256) void k_xt(const float* __restrict__ x,
                                            float* __restrict__ xt) {
    __shared__ float tile[GSIZE][XT_OTILE + 1];
    const int nob = N_OUT / XT_OTILE;            // 256
    const int g = blockIdx.x / nob;
    const int obase = (blockIdx.x % nob) * XT_OTILE;
    for (int i = threadIdx.x; i < GSIZE * XT_OTILE; i += 256) {
        int p = i >> 8;
        int oo = i & (XT_OTILE - 1);
        tile[p][oo] = x[((g * GSIZE + p) << 16) + obase + oo];
    }
    __syncthreads();
    for (int i = threadIdx.x; i < GSIZE * XT_OTILE; i += 256) {
        int oo = i >> 5;
        int p = i & 31;
        xt[(((size_t)(g << 16) + obase + oo) << 5) + p] = tile[p][oo];
    }
}

// ============================================================================
// Gather v4: entry-parallel, 32 planes/block, LDS accumulators, o-swept
// entry order (counting-sorted into (chunk, o>>7) buckets).
// Grid 8192 = 16 groups x 512 chunks; 2 groups pinned per XCD.
// ============================================================================
__global__ __launch_bounds__(GTH) void k_gather3(
    const float* __restrict__ x,
    const float* __restrict__ xt, int uxt,
    const int*   __restrict__ offsets,
    const int2*  __restrict__ entries,
    const unsigned* __restrict__ bits,
    float* __restrict__ out)
{
    __shared__ float acc[GSIZE * CHUNK];         // 64 KiB
    const int bid = blockIdx.x;
    const int xcd = bid & 7;
    const int r   = bid >> 3;                    // 0..1023
    const int g     = xcd * 2 + (r >> 9);
    const int chunk = r & (NCHUNKS - 1);
    const int n0    = chunk << 9;                // CHUNK == 512

    float4* a4 = (float4*)acc;
    for (int i = threadIdx.x; i < GSIZE * CHUNK / 4; i += GTH)
        a4[i] = float4{0.f, 0.f, 0.f, 0.f};
    __syncthreads();

    // chunk's entry range: keys [chunk<<9, (chunk+1)<<9)
    const int j0 = offsets[chunk << 9];
    const int j1 = offsets[(chunk << 9) + 512];
    const unsigned* bg = bits + ((size_t)(g * KK) << 16);

    if (uxt) {
        for (int j = j0 + threadIdx.x; j < j1; j += GTH) {
            const int2 e = entries[j];
            const unsigned u = (unsigned)e.x;
            const int o  = u >> 16;
            const int k  = (u >> 12) & 15;
            const int nl = u & (CHUNK - 1);
            const float w = __int_as_float(e.y);
            unsigned m = bg[(k << 16) + o];
            const float* xr = xt + (((size_t)(g << 16) + o) << 5);
            while (m) {
                int p = __ffs(m) - 1; m &= m - 1;
                atomicAdd(&acc[(p << 9) + nl], w * xr[p]);
            }
        }
    } else {
        for (int j = j0 + threadIdx.x; j < j1; j += GTH) {
            const int2 e = entries[j];
            const unsigned u = (unsigned)e.x;
            const int o  = u >> 16;
            const int k  = (u >> 12) & 15;
            const int nl = u & (CHUNK - 1);
            const float w = __int_as_float(e.y);
            unsigned m = bg[(k << 16) + o];
            const float* xr = x + ((size_t)(g * GSIZE) << 16) + o;
            while (m) {
                int p = __ffs(m) - 1; m &= m - 1;
                atomicAdd(&acc[(p << 9) + nl], w * xr[(size_t)p << 16]);
            }
        }
    }
    __syncthreads();

    // streamed (nontemporal) output stores: don't pollute L2/L3
    const f4_t* af = (const f4_t*)acc;
    for (int i = threadIdx.x; i < GSIZE * CHUNK / 4; i += GTH) {
        int p  = i >> 7;
        int n4 = i & 127;
        f4_t* dst = ((f4_t*)(out + (((size_t)(g * GSIZE + p)) << 18) + n0)) + n4;
        __builtin_nontemporal_store(af[i], dst);
    }
}

// ============================================================================
// Fallback (ws too small): round-1 atomic scatter
// ============================================================================
__global__ __launch_bounds__(256) void zero_kernel(float4* __restrict__ out, int n4) {
    int i = blockIdx.x * blockDim.x + threadIdx.x;
    int stride = gridDim.x * blockDim.x;
    const float4 z = {0.f, 0.f, 0.f, 0.f};
    for (; i < n4; i += stride) out[i] = z;
}

__global__ __launch_bounds__(256) void scatter_kernel(
    const float* __restrict__ x, const int* __restrict__ idx_mask,
    const int4* __restrict__ smap, const float4* __restrict__ wts,
    float* __restrict__ out)
{
    const int plane = blockIdx.x >> 8;
    const int o = ((blockIdx.x & 255) << 8) + threadIdx.x;
    const long ibase = (long)plane * N_OUT + o;
    const float xv = x[ibase];
    const int k = idx_mask[ibase];
    const int row = o * KK + k;
    const int4 m = smap[row];
    const float4 w = wts[row];
    float* op = out + (long)plane * N_IN;
    atomicAdd(op + m.x, w.x * xv);
    atomicAdd(op + m.y, w.y * xv);
    atomicAdd(op + m.z, w.z * xv);
    atomicAdd(op + m.w, w.w * xv);
}

// ============================================================================
extern "C" void kernel_launch(void* const* d_in, const int* in_sizes, int n_in,
                              void* d_out, int out_size, void* d_ws, size_t ws_size,
                              hipStream_t stream) {
    const float* x    = (const float*)d_in[0];
    const int*   idx  = (const int*)d_in[1];
    const int*   smap = (const int*)d_in[2];
    const float* wts  = (const float*)d_in[3];
    float* out = (float*)d_out;

    const size_t need_full = (size_t)WS_END_FULL * 4;   // ~185 MiB
    const size_t need_noxt = (size_t)WS_END_NOXT * 4;   // ~57 MiB

    if (ws_size < need_noxt) {
        zero_kernel<<<4096, 256, 0, stream>>>((float4*)out, out_size / 4);
        scatter_kernel<<<(NPLANES) * (N_OUT / 256), 256, 0, stream>>>(
            x, idx, (const int4*)smap, (const float4*)wts, out);
        return;
    }

    int* ws = (int*)d_ws;
    int* counts   = ws + WS_COUNTS;
    int* cursor   = ws + WS_CURSOR;
    int* offsets  = ws + WS_OFFSETS;
    int* bsum     = ws + WS_BSUM;
    int2* entries = (int2*)(ws + WS_ENTRIES);
    unsigned* bits = (unsigned*)(ws + WS_BITS);
    float* xt      = (float*)(ws + WS_XT);
    const int uxt = (ws_size >= need_full) ? 1 : 0;

    // 1) zero counts + cursor
    k_zero_ints<<<512, 256, 0, stream>>>(counts, (2 * N_IN) / 4);
    // 2) histogram over (chunk, o>>7) sort keys
    k_hist<<<NE / 256, 256, 0, stream>>>(smap, counts);
    // 3) exclusive scan -> offsets
    k_scanA<<<256, 256, 0, stream>>>(counts, offsets, bsum);
    k_scanB<<<1, 256, 0, stream>>>(bsum);
    k_scanC<<<256, 256, 0, stream>>>(offsets, bsum);
    // 4) fill entries, counting-sorted by (chunk, o>>7)
    k_fill<<<NE / 256, 256, 0, stream>>>(smap, wts, offsets, cursor, entries);
    // 5) per-group k-match bitmasks
    k_bits<<<NGROUPS * (N_OUT / BITS_OTILE), 256, 0, stream>>>(idx, bits);
    // 6) plane-transposed x (optional)
    if (uxt) k_xt<<<NGROUPS * (N_OUT / XT_OTILE), 256, 0, stream>>>(x, xt);
    // 7) entry-parallel gather, o-swept
    k_gather3<<<NGROUPS * NCHUNKS, GTH, 0, stream>>>(x, xt, uxt, offsets, entries, bits, out);
}

// Round 6
// 1090.258 us; speedup vs baseline: 5.9262x; 1.0765x over previous
//
#include <hip/hip_runtime.h>

// x:              [B, C, N_OUT]  f32   (512 planes x 65536)
// idx_mask:       [B, C, N_OUT]  i32 in [0, K)
// sample_map:     [N_OUT, K, P]  i32 in [0, N_IN)
// interp_weights: [N_OUT, K, P]  f32
// out:            [B, C, N_IN]   f32
#define BB      8
#define CC      64
#define N_OUT   65536
#define N_IN    262144
#define KK      9
#define PP      4
#define NE      (N_OUT * KK * PP)   // 2,359,296
#define NPLANES 512
#define CHUNK   32                  // n per gather block
#define NCHUNKS (N_IN / CHUNK)      // 8192
#define GTH     512                 // gather threads (8 waves)
#define NW      (GTH / 64)

// ---------------- d_ws layout (int units) ----------------
// counts  [8192]        chunk histogram
// cursor  [8192]
// offsets [8193] (+pad)
// hdr     [N_OUT*9] u32 = start | (cnt<<16) per (o,k)
// entries int4[NE]      {(o<<5)|nl, w_bits, start|(cnt<<16), 0}
// xk      u32[N_OUT*512] per o: planes k-sorted, (x_bits & ~511) | plane_id
#define WS_COUNTS  0
#define WS_CURSOR  8192
#define WS_OFFSETS 16384
#define WS_HDR     24640
#define WS_ENTR    614464            // 16B aligned
#define WS_XK      10051648
#define WS_END     43606080          // ints (~166.4 MiB)

// ============================================================================
__global__ __launch_bounds__(256) void k_zero_ints(int* __restrict__ p, int n4) {
    int i = blockIdx.x * 256 + threadIdx.x;
    int stride = gridDim.x * 256;
    const int4 z = {0, 0, 0, 0};
    for (; i < n4; i += stride) ((int4*)p)[i] = z;
}

// ============================================================================
// k_xk: per o, sort the 512 planes' x by their idx_mask tap k.
//   xk[o][j] (j in k-sorted order) = (x_bits & 0xFFFFFE00) | plane_id (9 bits)
//   hdr[o*9+k] = start | (cnt << 16)
// ============================================================================
#define XKTILE 16
#define XPAD   520
__global__ __launch_bounds__(256) void k_xk(const float* __restrict__ x,
                                            const int*   __restrict__ idx,
                                            unsigned* __restrict__ xk,
                                            unsigned* __restrict__ hdr) {
    __shared__ float xs[XKTILE * XPAD];          // 33.3 KB [oo][p] padded
    __shared__ unsigned char ks[XKTILE * XPAD];  // 8.3 KB
    __shared__ unsigned ot[XKTILE * 512];        // 32 KB out tile
    __shared__ int cnt[XKTILE][12];
    __shared__ int cur[XKTILE][12];
    const int t = threadIdx.x;
    const int obase = blockIdx.x * XKTILE;

    for (int i = t; i < XKTILE * 12; i += 256) cnt[i / 12][i % 12] = 0;

    // load x/idx tile: 512 planes x 16 o's, 16B vector loads
    for (int i = t; i < 512 * (XKTILE / 4); i += 256) {   // 2048
        int p = i >> 2, q = i & 3;
        const size_t g = (size_t)p * N_OUT + obase + 4 * q;
        float4 xv = *(const float4*)(x + g);
        int4   kv = *(const int4*)(idx + g);
        int b = (4 * q) * XPAD + p;
        xs[b] = xv.x; xs[b + XPAD] = xv.y; xs[b + 2 * XPAD] = xv.z; xs[b + 3 * XPAD] = xv.w;
        ks[b] = (unsigned char)kv.x; ks[b + XPAD] = (unsigned char)kv.y;
        ks[b + 2 * XPAD] = (unsigned char)kv.z; ks[b + 3 * XPAD] = (unsigned char)kv.w;
    }
    __syncthreads();
    // count
    for (int i = t; i < XKTILE * 512; i += 256) {
        int oo = i >> 9, p = i & 511;
        atomicAdd(&cnt[oo][ks[oo * XPAD + p]], 1);
    }
    __syncthreads();
    // prefix + header write
    if (t < XKTILE) {
        int s = 0;
        for (int k = 0; k < KK; ++k) {
            int c = cnt[t][k];
            cur[t][k] = s;
            hdr[(size_t)(obase + t) * KK + k] = (unsigned)(s | (c << 16));
            s += c;
        }
    }
    __syncthreads();
    // place (k-sorted runs, order within run arbitrary)
    for (int i = t; i < XKTILE * 512; i += 256) {
        int oo = i >> 9, p = i & 511;
        int k = ks[oo * XPAD + p];
        int pos = atomicAdd(&cur[oo][k], 1);
        unsigned xb = __float_as_uint(xs[oo * XPAD + p]);
        ot[(oo << 9) + pos] = (xb & 0xFFFFFE00u) | (unsigned)p;
    }
    __syncthreads();
    // flush 16 rows x 2 KB coalesced
    for (int i = t; i < XKTILE * 128; i += 256) {
        int oo = i >> 7, c4 = i & 127;
        ((int4*)(xk + (((size_t)(obase + oo)) << 9)))[c4] = ((const int4*)(ot + (oo << 9)))[c4];
    }
}

// ============================================================================
// histogram over n-chunks (key = n>>5, 8192 keys)
// ============================================================================
__global__ __launch_bounds__(256) void k_hist5(const int* __restrict__ smap,
                                               int* __restrict__ counts) {
    int e = blockIdx.x * 256 + threadIdx.x;
    if (e < NE) atomicAdd(&counts[smap[e] >> 5], 1);
}

// single-block exclusive scan over 8192 counters
__global__ __launch_bounds__(1024) void k_scan8k(const int* __restrict__ counts,
                                                 int* __restrict__ offsets) {
    __shared__ int sw[1024];
    const int t = threadIdx.x;
    int4 a = ((const int4*)counts)[2 * t];
    int4 b = ((const int4*)counts)[2 * t + 1];
    int s = a.x + a.y + a.z + a.w + b.x + b.y + b.z + b.w;
    sw[t] = s;
    __syncthreads();
    for (int off = 1; off < 1024; off <<= 1) {
        int v = (t >= off) ? sw[t - off] : 0;
        __syncthreads();
        sw[t] += v;
        __syncthreads();
    }
    int run = sw[t] - s;
    int vals[8] = {a.x, a.y, a.z, a.w, b.x, b.y, b.z, b.w};
    int o[8];
    #pragma unroll
    for (int q = 0; q < 8; ++q) { o[q] = run; run += vals[q]; }
    ((int4*)offsets)[2 * t]     = make_int4(o[0], o[1], o[2], o[3]);
    ((int4*)offsets)[2 * t + 1] = make_int4(o[4], o[5], o[6], o[7]);
    if (t == 1023) offsets[8192] = NE;
}

// fill entries into chunk buckets; embed (start,cnt) from hdr
__global__ __launch_bounds__(256) void k_fill5(const int* __restrict__ smap,
                                               const float* __restrict__ wts,
                                               const int* __restrict__ offsets,
                                               int* __restrict__ cursor,
                                               const unsigned* __restrict__ hdr,
                                               int4* __restrict__ entries) {
    int e = blockIdx.x * 256 + threadIdx.x;
    if (e >= NE) return;
    int n = smap[e];
    int o = e / 36;                 // e = o*36 + k*4 + p_tap
    int r = e - o * 36;
    int k = r >> 2;
    unsigned h = hdr[(size_t)o * KK + k];
    int key = n >> 5;
    int pos = offsets[key] + atomicAdd(&cursor[key], 1);
    entries[pos] = make_int4((o << 5) | (n & 31), __float_as_int(wts[e]), (int)h, 0);
}

// ============================================================================
// Gather v5: block = one 32-n chunk x ALL 512 planes. Wave-per-entry:
// lane l reads the k-sorted run xk[o][start+l] (coalesced 256 B) and
// ds_adds into acc[nl][p^nl] (XOR swizzle -> conflict-free flush).
// 2-deep software pipeline hides the entry->xk chain. Entries read ONCE.
// ============================================================================
__global__ __launch_bounds__(GTH) void k_gather5(const int* __restrict__ offsets,
                                                 const int4* __restrict__ entries,
                                                 const unsigned* __restrict__ xk,
                                                 float* __restrict__ out) {
    __shared__ float acc[CHUNK * NPLANES];       // 64 KB
    const int c = blockIdx.x;
    const int tid = threadIdx.x;
    const int lane = tid & 63;
    const int wid = tid >> 6;

    float4* a4 = (float4*)acc;
    for (int i = tid; i < CHUNK * NPLANES / 4; i += GTH) a4[i] = float4{0.f, 0.f, 0.f, 0.f};
    __syncthreads();

    const int j1 = offsets[c + 1];
    int j = offsets[c] + wid;
    int4 e = make_int4(0, 0, 0, 0);
    unsigned u0 = 0;
    bool have = (j < j1);
    if (have) {
        e = entries[j];
        int o = ((unsigned)e.x) >> 5;
        int st = e.z & 0xFFFF;
        int cn = ((unsigned)e.z) >> 16;
        if (lane < cn) u0 = xk[((size_t)o << 9) + st + lane];
    }
    while (have) {
        const int jn = j + NW;
        const bool hn = (jn < j1);
        int4 en = make_int4(0, 0, 0, 0);
        unsigned un = 0;
        if (hn) {
            en = entries[jn];
            int on = ((unsigned)en.x) >> 5;
            int stn = en.z & 0xFFFF;
            int cnn = ((unsigned)en.z) >> 16;
            if (lane < cnn) un = xk[((size_t)on << 9) + stn + lane];
        }
        {
            const int nl = e.x & 31;
            const float w = __int_as_float(e.y);
            const int cn = ((unsigned)e.z) >> 16;
            if (lane < cn) {
                int p = u0 & 511;
                float xv = __int_as_float(u0 & 0xFFFFFE00u);
                atomicAdd(&acc[(nl << 9) + (p ^ nl)], w * xv);
            }
            if (cn > 64) {                       // rare (P(cnt>64) ~ 16%)
                const int o = ((unsigned)e.x) >> 5;
                const int st = e.z & 0xFFFF;
                for (int b = lane + 64; b < cn; b += 64) {
                    unsigned u = xk[((size_t)o << 9) + st + b];
                    int p = u & 511;
                    float xv = __int_as_float(u & 0xFFFFFE00u);
                    atomicAdd(&acc[(nl << 9) + (p ^ nl)], w * xv);
                }
            }
        }
        e = en; u0 = un; j = jn; have = hn;
    }
    __syncthreads();

    // flush: lanes 0..31 -> consecutive nl -> 128 B coalesced per p-row.
    // LDS read bank = (p^nl)%32, nl spans 0..31 -> conflict-free.
    const int n0 = c << 5;
    for (int i = tid; i < CHUNK * NPLANES; i += GTH) {
        int p = i >> 5, nl = i & 31;
        __builtin_nontemporal_store(acc[(nl << 9) + (p ^ nl)],
                                    out + (size_t)p * N_IN + n0 + nl);
    }
}

// ============================================================================
// Fallback (ws too small): round-1 atomic scatter
// ============================================================================
__global__ __launch_bounds__(256) void zero_kernel(float4* __restrict__ out, int n4) {
    int i = blockIdx.x * blockDim.x + threadIdx.x;
    int stride = gridDim.x * blockDim.x;
    const float4 z = {0.f, 0.f, 0.f, 0.f};
    for (; i < n4; i += stride) out[i] = z;
}

__global__ __launch_bounds__(256) void scatter_kernel(
    const float* __restrict__ x, const int* __restrict__ idx_mask,
    const int4* __restrict__ smap, const float4* __restrict__ wts,
    float* __restrict__ out)
{
    const int plane = blockIdx.x >> 8;
    const int o = ((blockIdx.x & 255) << 8) + threadIdx.x;
    const long ibase = (long)plane * N_OUT + o;
    const float xv = x[ibase];
    const int k = idx_mask[ibase];
    const int row = o * KK + k;
    const int4 m = smap[row];
    const float4 w = wts[row];
    float* op = out + (long)plane * N_IN;
    atomicAdd(op + m.x, w.x * xv);
    atomicAdd(op + m.y, w.y * xv);
    atomicAdd(op + m.z, w.z * xv);
    atomicAdd(op + m.w, w.w * xv);
}

// ============================================================================
extern "C" void kernel_launch(void* const* d_in, const int* in_sizes, int n_in,
                              void* d_out, int out_size, void* d_ws, size_t ws_size,
                              hipStream_t stream) {
    const float* x    = (const float*)d_in[0];
    const int*   idx  = (const int*)d_in[1];
    const int*   smap = (const int*)d_in[2];
    const float* wts  = (const float*)d_in[3];
    float* out = (float*)d_out;

    if (ws_size < (size_t)WS_END * 4) {
        zero_kernel<<<4096, 256, 0, stream>>>((float4*)out, out_size / 4);
        scatter_kernel<<<NPLANES * (N_OUT / 256), 256, 0, stream>>>(
            x, idx, (const int4*)smap, (const float4*)wts, out);
        return;
    }

    int* ws = (int*)d_ws;
    int* counts    = ws + WS_COUNTS;
    int* cursor    = ws + WS_CURSOR;
    int* offsets   = ws + WS_OFFSETS;
    unsigned* hdr  = (unsigned*)(ws + WS_HDR);
    int4* entries  = (int4*)(ws + WS_ENTR);
    unsigned* xk   = (unsigned*)(ws + WS_XK);

    // 1) zero counts+cursor (16384 ints)
    k_zero_ints<<<16, 256, 0, stream>>>(counts, 16384 / 4);
    // 2) k-sorted xk + headers
    k_xk<<<N_OUT / XKTILE, 256, 0, stream>>>(x, idx, xk, hdr);
    // 3) chunk histogram
    k_hist5<<<NE / 256, 256, 0, stream>>>(smap, counts);
    // 4) scan (8192 keys, one block)
    k_scan8k<<<1, 1024, 0, stream>>>(counts, offsets);
    // 5) fill entries (embeds start/cnt from hdr)
    k_fill5<<<NE / 256, 256, 0, stream>>>(smap, wts, offsets, cursor, hdr, entries);
    // 6) gather: one block per 32-n chunk, all 512 planes
    k_gather5<<<NCHUNKS, GTH, 0, stream>>>(offsets, entries, xk, out);
}